// Round 4
// baseline (401.112 us; speedup 1.0000x reference)
//
#include <hip/hip_runtime.h>
#include <hip/hip_bf16.h>
#include <math.h>

// KAN layer, fully fused: per K-step (8 input dims) each block featurizes its
// 128 rows on the fly (wave = dim -> params in SGPRs, float2 packed pair math),
// writes fp16 features to a padded LDS A-tile, streams packed weights into a
// linear LDS B-tile via global_load_lds, and MFMAs. y = tanh(F@W^T + rs*x).

#define IN_DIM  512
#define OUT_DIM 512
#define FPI     12
#define KTOT    (IN_DIM * FPI)    // 6144
#define NBATCH  16384

#define PSTRIDE 64
// P per-dim row (stride 64 f32): t[0..14]@0 | i1[0..13]@15 | i2[0..12]@29 | i3[0..11]@42
#define WS_WH_OFF_F (PSTRIDE * IN_DIM)   // floats

#define BMF 128     // rows per block
#define BNF 256     // cols per block
#define KS  96      // halfs per K-step (8 dims * 12)
#define LDA 104     // padded A stride (halfs): 52-dword rows -> conflict-free b128
#define NSTEPS 64   // 512 dims / 8

typedef _Float16 half8 __attribute__((ext_vector_type(8)));
typedef _Float16 half4 __attribute__((ext_vector_type(4)));
typedef float f32x4 __attribute__((ext_vector_type(4)));
typedef float f32x2 __attribute__((ext_vector_type(2)));

__device__ __forceinline__ void gload16(const void* g, void* l) {
    __builtin_amdgcn_global_load_lds((const __attribute__((address_space(1))) void*)g,
                                     (__attribute__((address_space(3))) void*)l, 16, 0, 0);
}

// ---------------- kernel 1: per-dim knots + inverse denominators -----------
__global__ void kan_prep(const float* __restrict__ gsl, const float* __restrict__ gstart,
                         float* __restrict__ P) {
    int i = blockIdx.x * 256 + threadIdx.x;
    if (i >= IN_DIM) return;
    float t[15];
    float a = gstart[i];
    t[0] = a;
#pragma unroll
    for (int m = 0; m < 14; ++m) {
        float z = gsl[i * 14 + m];
        a += fmaxf(z, 0.f) + log1pf(__expf(-fabsf(z)));   // stable softplus
        t[m + 1] = a;
    }
    float* p = P + (size_t)i * PSTRIDE;
#pragma unroll
    for (int m = 0; m < 15; ++m) p[m] = t[m];
#pragma unroll
    for (int m = 0; m < 14; ++m) { float d = t[m+1] - t[m]; p[15+m] = 1.f / ((d == 0.f) ? 1.f : d); }
#pragma unroll
    for (int m = 0; m < 13; ++m) { float d = t[m+2] - t[m]; p[29+m] = 1.f / ((d == 0.f) ? 1.f : d); }
#pragma unroll
    for (int m = 0; m < 12; ++m) { float d = t[m+3] - t[m]; p[42+m] = 1.f / ((d == 0.f) ? 1.f : d); }
#pragma unroll
    for (int m = 54; m < 64; ++m) p[m] = 0.f;
}

// ---------------- kernel 2: pack [coeffs | base_weight] to fp16 ------------
__global__ void kan_packw(const float* __restrict__ coeffs, const float* __restrict__ bw,
                          _Float16* __restrict__ Wh) {
    int idx = blockIdx.x * 256 + threadIdx.x;   // idx = o*512 + i
    const float* src = coeffs + (size_t)idx * 11;
    union { _Float16 h[12]; float2 f2[3]; } u;
#pragma unroll
    for (int c = 0; c < 11; ++c) u.h[c] = (_Float16)src[c];
    u.h[11] = (_Float16)bw[idx];
    float2* dst = (float2*)(Wh + (size_t)idx * FPI);
    dst[0] = u.f2[0]; dst[1] = u.f2[1]; dst[2] = u.f2[2];
}

// ---------------- kernel 3: fused featurize + GEMM + epilogue --------------
__launch_bounds__(512, 4)
__global__ void kan_fused(const float* __restrict__ x, const float* __restrict__ P,
                          const _Float16* __restrict__ Wh, const float* __restrict__ rsp,
                          float* __restrict__ out) {
    __shared__ __align__(16) _Float16 Al[BMF][LDA];   // 26,624 B
    __shared__ __align__(16) _Float16 Bl[BNF][KS];    // 49,152 B
    __shared__ __align__(16) float    xl[BMF][10];    //  5,120 B (pad 10 -> bank-spread)

    const int tid = threadIdx.x;
    const int l = tid & 63;
    const int w = __builtin_amdgcn_readfirstlane(tid >> 6);  // wave id 0..7 (scalar)
    const int bid = blockIdx.x;
    const int rt = bid >> 1, ct = bid & 1;    // pairs share rows -> x L2 locality
    const int b0 = rt * BMF, o0 = ct * BNF;

    // MFMA geometry: 8 waves = 2(row) x 4(col) tiles of 64x64
    const int wr = (w >> 2) * 64;
    const int wc = (w & 3) * 64;

    f32x4 acc[4][4];
    const f32x4 zz = {0.f, 0.f, 0.f, 0.f};
#pragma unroll
    for (int m = 0; m < 4; ++m)
#pragma unroll
        for (int n = 0; n < 4; ++n) acc[m][n] = zz;

    // B staging: 3072 x 16B chunks; thread owns chunks tid + i*512
    int ofsB[6];
#pragma unroll
    for (int i = 0; i < 6; ++i) {
        int c = tid + i * 512;
        int row = c / 12, off = c - row * 12;
        ofsB[i] = ((o0 + row) * KTOT + off * 8) * 2;   // bytes into Wh
    }
    char* BlFlat = (char*)&Bl[0][0];

    // prologue: stage x-tile for step 0
    if (tid < 256) {
        int row = tid >> 1, part = tid & 1;
        float4 v = *(const float4*)&x[(size_t)(b0 + row) * IN_DIM + part * 4];
        *(f32x2*)&xl[row][part * 4]     = f32x2{v.x, v.y};
        *(f32x2*)&xl[row][part * 4 + 2] = f32x2{v.z, v.w};
    }
    __syncthreads();

    for (int s = 0; s < NSTEPS; ++s) {
        // --- issue B tile loads (in flight during featurize) ---
#pragma unroll
        for (int i = 0; i < 6; ++i)
            gload16((const char*)Wh + (ofsB[i] + s * (KS * 2)), BlFlat + tid * 16 + i * 8192);

        // --- featurize: dim = s*8 + w, point-pair rows (l, l+64) ---
        {
            const float* ps = P + (size_t)(s * 8 + w) * PSTRIDE;   // wave-uniform -> s_load
            f32x2 X = { xl[l][w], xl[l + 64][w] };
            f32x2 b[14];
#pragma unroll
            for (int m = 0; m < 14; ++m) {
                float tm = ps[m], tm1 = ps[m + 1];
                b[m].x = (X.x >= tm && X.x < tm1) ? 1.f : 0.f;
                b[m].y = (X.y >= tm && X.y < tm1) ? 1.f : 0.f;
            }
#pragma unroll
            for (int m = 0; m < 13; ++m) {
                f32x2 dm = X - ps[m];
                f32x2 dp = X - ps[m + 2];
                b[m] = (dm * ps[15 + m]) * b[m] - (dp * ps[16 + m]) * b[m + 1];
            }
#pragma unroll
            for (int m = 0; m < 12; ++m) {
                f32x2 dm = X - ps[m];
                f32x2 dp = X - ps[m + 3];
                b[m] = (dm * ps[29 + m]) * b[m] - (dp * ps[30 + m]) * b[m + 1];
            }
#pragma unroll
            for (int m = 0; m < 11; ++m) {
                f32x2 dm = X - ps[m];
                f32x2 dp = X - ps[m + 4];
                b[m] = (dm * ps[42 + m]) * b[m] - (dp * ps[43 + m]) * b[m + 1];
            }
            f32x2 sil;
            sil.x = X.x / (1.f + __expf(-X.x));
            sil.y = X.y / (1.f + __expf(-X.y));
#pragma unroll
            for (int pt = 0; pt < 2; ++pt) {
                const int row = l + pt * 64;
#define BC(m) (pt ? b[m].y : b[m].x)
                half4 h0 = { (_Float16)BC(0), (_Float16)BC(1), (_Float16)BC(2), (_Float16)BC(3) };
                half4 h1 = { (_Float16)BC(4), (_Float16)BC(5), (_Float16)BC(6), (_Float16)BC(7) };
                half4 h2 = { (_Float16)BC(8), (_Float16)BC(9), (_Float16)BC(10),
                             (_Float16)(pt ? sil.y : sil.x) };
#undef BC
                *(half4*)&Al[row][w * 12]     = h0;
                *(half4*)&Al[row][w * 12 + 4] = h1;
                *(half4*)&Al[row][w * 12 + 8] = h2;
            }
        }
        __syncthreads();   // A writes + B gloads drained (compiler vmcnt(0))

        // --- stage x-tile for next step (latency hides under MFMA) ---
        if (s + 1 < NSTEPS && tid < 256) {
            int row = tid >> 1, part = tid & 1;
            float4 v = *(const float4*)&x[(size_t)(b0 + row) * IN_DIM + (s + 1) * 8 + part * 4];
            *(f32x2*)&xl[row][part * 4]     = f32x2{v.x, v.y};
            *(f32x2*)&xl[row][part * 4 + 2] = f32x2{v.z, v.w};
        }

        // --- MFMA: wave computes 64x64 via 4x4 frags, K=96 ---
        {
            const int ar = wr + (l & 15);
            const int bc = wc + (l & 15);
            const int ko = (l >> 4) * 8;
#pragma unroll
            for (int kk = 0; kk < 3; ++kk) {
                half8 af[4], bf[4];
#pragma unroll
                for (int m = 0; m < 4; ++m) af[m] = *(const half8*)&Al[ar + m * 16][kk * 32 + ko];
#pragma unroll
                for (int n = 0; n < 4; ++n) bf[n] = *(const half8*)&Bl[bc + n * 16][kk * 32 + ko];
#pragma unroll
                for (int m = 0; m < 4; ++m)
#pragma unroll
                    for (int n = 0; n < 4; ++n)
                        acc[m][n] = __builtin_amdgcn_mfma_f32_16x16x32_f16(af[m], bf[n], acc[m][n], 0, 0, 0);
            }
        }
        __syncthreads();   // xl(s+1) visible; MFMA reads done before overwrite
    }

    // --- epilogue: + rs*x, tanh, store ---
    const float rs = rsp[0];
#pragma unroll
    for (int m = 0; m < 4; ++m)
#pragma unroll
        for (int n = 0; n < 4; ++n)
#pragma unroll
            for (int j = 0; j < 4; ++j) {
                const int r = b0 + wr + m * 16 + (l >> 4) * 4 + j;
                const int c = o0 + wc + n * 16 + (l & 15);
                float v = acc[m][n][j] + rs * x[(size_t)r * IN_DIM + c];
                float e = __expf(2.f * v);            // tanh = 1 - 2/(e^2v+1)
                out[(size_t)r * OUT_DIM + c] = 1.f - 2.f / (e + 1.f);
            }
}

extern "C" void kernel_launch(void* const* d_in, const int* in_sizes, int n_in,
                              void* d_out, int out_size, void* d_ws, size_t ws_size,
                              hipStream_t stream) {
    const float* x      = (const float*)d_in[0];
    const float* coeffs = (const float*)d_in[1];
    const float* bw     = (const float*)d_in[2];
    const float* gsl    = (const float*)d_in[3];
    const float* gstart = (const float*)d_in[4];
    const float* rs     = (const float*)d_in[5];
    float* out = (float*)d_out;
    float* P   = (float*)d_ws;
    _Float16* Wh = (_Float16*)(P + WS_WH_OFF_F);

    kan_prep<<<2, 256, 0, stream>>>(gsl, gstart, P);
    kan_packw<<<1024, 256, 0, stream>>>(coeffs, bw, Wh);
    kan_fused<<<(NBATCH / BMF) * (OUT_DIM / BNF), 512, 0, stream>>>(x, P, Wh, rs, out);
}